// Round 13
// baseline (198.418 us; speedup 1.0000x reference)
//
#include <hip/hip_runtime.h>
#include <hip/hip_bf16.h>
#include <cstddef>

// m_in  raw-viewed as mi [128][16384]   fp32
// m_out raw-viewed as mo [512][16384]   fp32
// q_in  = qi [4][128][1024]             fp32
// q_out = qo [4][512][1024]             fp32
// out0  = mem_out [4][1024][1024]  (ch 0..511 = mem, ch 512..1023 = q_out copy)
// out1  = p [4][16384][1024] softmax over the 16384 axis
//
// ws layout (big path, gate ws_size >= 176160768):
//   [0, 64MB)        e8  fp8 e4m3 [4][1024][16384]
//   [64MB, 72MB)     mo8 fp8 e4m3 [512][16384]
//   [72MB, 96MB)     split-K partials: 3 x 2M fp32
//   [96MB, 98MB)     partial colsums [128][4][1024] fp32
//   [98MB, +16KB)    invsum [4][1024] fp32

#define DE   128
#define DO   512
#define NMEM 16384
#define QCOL 1024

typedef __attribute__((ext_vector_type(8))) short    short8v;
typedef __attribute__((ext_vector_type(8))) _Float16 half8v;
typedef __attribute__((ext_vector_type(4))) float    f32x4;
typedef __attribute__((ext_vector_type(2))) float    f32x2;
typedef __attribute__((ext_vector_type(2))) unsigned u32x2;
typedef __attribute__((ext_vector_type(4))) unsigned u32x4;

__device__ __forceinline__ short f2bf(float x) {
    union { __hip_bfloat16 h; short s; } u;
    u.h = __float2bfloat16(x);
    return u.s;
}

// pack 4 f32 -> 4 fp8(e4m3) in a u32
__device__ __forceinline__ unsigned pk_fp8x4(float f0, float f1, float f2, float f3) {
    unsigned r = __builtin_amdgcn_cvt_pk_fp8_f32(f0, f1, 0, false);
    r = __builtin_amdgcn_cvt_pk_fp8_f32(f2, f3, r, true);
    return r;
}

// bank-balancing XOR swizzle (granule-level), bijective per 8-row stripe
#define FSW(r) ((((r) >> 3) ^ (r)) & 7)

__device__ __forceinline__ void gl16c(const unsigned char* g, unsigned char* l) {
    __builtin_amdgcn_global_load_lds(
        (const __attribute__((address_space(1))) void*)g,
        (__attribute__((address_space(3))) void*)l, 16, 0, 0);
}

// ===========================================================================
// BIG-WS PATH (fp8)
// ===========================================================================

// K1 (+conv8 fused as tail blocks): bids < 4096 compute scores; bids >= 4096
// convert mo->mo8 (overlaps into k1's tail; k4 consumes mo8 much later).
// Scores: C[n][q] = sum_d mi[d][n]*qi[d][q] via f16 MFMA, e=exp -> e8 fp8
// [b][q][n] + per-128n-tile colsums. Block 128q x 128n, K=128 one-shot.
// XCD-grouped: bid%8 keys (nt,b)-group so the 8 qt-blocks sharing an mi tile
// land on one XCD.
__global__ __launch_bounds__(256, 2)
void k1_mfma(const float* __restrict__ mi, const float* __restrict__ qi,
             const float* __restrict__ mo,
             unsigned char* __restrict__ e8, unsigned char* __restrict__ mo8,
             float* __restrict__ partial)
{
    const int bid = blockIdx.x;
    if (bid >= 4096) {
        // ---- conv8 tail: mo fp32 -> mo8 fp8, 1024 blocks x 256 thr x 4 units
        const size_t u = (size_t)(bid - 4096) * 256 + threadIdx.x;
#pragma unroll
        for (int r = 0; r < 4; ++r) {
            const size_t i = (u + (size_t)r * 262144) << 3;
            f32x4 a = *(const f32x4*)(mo + i);
            f32x4 c = *(const f32x4*)(mo + i + 4);
            u32x2 v;
            v[0] = pk_fp8x4(a[0], a[1], a[2], a[3]);
            v[1] = pk_fp8x4(c[0], c[1], c[2], c[3]);
            *(u32x2*)(mo8 + i) = v;
        }
        return;
    }

    // decode XCD-grouped flat id: bid = c + 8*(qt + 8*ghi); g = ghi*8+c
    const int c   = bid & 7;
    const int r   = bid >> 3;
    const int qt  = r & 7;
    const int g   = ((r >> 3) << 3) | c;   // 0..511
    const int nt  = g & 127;
    const int b   = g >> 7;
    const int qb  = qt << 7;
    const int nb  = nt << 7;

    __shared__ __align__(16) short AfBf[2][128 * 128]; // f16 as shorts
    __shared__ float red2[2][128];

    short* Bq = AfBf[0];   // [q][d] swizzled (B operand)
    short* An = AfBf[1];   // [n][d] swizzled (A operand)
    unsigned char* T8 = (unsigned char*)AfBf[0];  // reused: [q][n] fp8 swizzled

    const int tid  = threadIdx.x;
    const int lane = tid & 63;
    const int w    = tid >> 6;
    const int wn2  = (w >> 1) << 6;   // n-half 0/64
    const int wq   = (w & 1) << 6;    // q-half 0/64
    const int la   = lane & 15;
    const int kg   = lane >> 4;

    // staging: thread covers 8 d-rows x (2 x 4 cols), reg-transpose, swizzled
    {
        const int d8 = (tid >> 4) << 3;       // 0..120
        const int c4 = (tid & 15) << 2;       // 0..60
        const float* qib = qi + (size_t)b * (DE * QCOL) + (size_t)d8 * QCOL + qb;
        const float* mib = mi + (size_t)d8 * NMEM + nb;
#pragma unroll
        for (int half = 0; half < 2; ++half) {
            const int cc = c4 + (half << 6);  // 0..124
            f32x4 qv[8], mv[8];
#pragma unroll
            for (int i = 0; i < 8; ++i) {
                qv[i] = *(const f32x4*)(qib + (size_t)i * QCOL + cc);
                mv[i] = *(const f32x4*)(mib + (size_t)i * NMEM + cc);
            }
#pragma unroll
            for (int j = 0; j < 4; ++j) {
                const int row = cc + j;
                const int off = row * 128 + ((((d8 >> 3) ^ FSW(row))) << 3);
                half8v av, bv;
#pragma unroll
                for (int i = 0; i < 8; ++i) {
                    av[i] = (_Float16)qv[i][j];
                    bv[i] = (_Float16)mv[i][j];
                }
                *(half8v*)&Bq[off] = av;
                *(half8v*)&An[off] = bv;
            }
        }
    }
    __syncthreads();

    // MFMA: acc[fm][fn]: row n = wn2+fm*16+(kg<<2)+r ; col q = wq+fn*16+la
    f32x4 acc[4][4];
#pragma unroll
    for (int i = 0; i < 4; ++i)
#pragma unroll
        for (int j = 0; j < 4; ++j) acc[i][j] = (f32x4){0.f, 0.f, 0.f, 0.f};

#pragma unroll
    for (int ks = 0; ks < 4; ++ks) {
        half8v af[4], bf[4];
#pragma unroll
        for (int f = 0; f < 4; ++f) {
            const int ra = wn2 + f * 16 + la;   // A rows: n
            const int rb = wq  + f * 16 + la;   // B rows: q
            af[f] = *(const half8v*)&An[ra * 128 + ((((ks << 2) + kg) ^ FSW(ra)) << 3)];
            bf[f] = *(const half8v*)&Bq[rb * 128 + ((((ks << 2) + kg) ^ FSW(rb)) << 3)];
        }
#pragma unroll
        for (int fm = 0; fm < 4; ++fm)
#pragma unroll
            for (int fn = 0; fn < 4; ++fn)
                acc[fm][fn] = __builtin_amdgcn_mfma_f32_16x16x32_f16(
                    af[fm], bf[fn], acc[fm][fn], 0, 0, 0);
    }

    const float scale = 0.08838834764831845f; // 1/sqrt(128)
#pragma unroll
    for (int fm = 0; fm < 4; ++fm)
#pragma unroll
        for (int fn = 0; fn < 4; ++fn)
#pragma unroll
            for (int rr = 0; rr < 4; ++rr)
                acc[fm][fn][rr] = __expf(acc[fm][fn][rr] * scale);

    // colsum over n per q-col
    float val[4];
#pragma unroll
    for (int fn = 0; fn < 4; ++fn) {
        float s = 0.f;
#pragma unroll
        for (int fm = 0; fm < 4; ++fm)
#pragma unroll
            for (int rr = 0; rr < 4; ++rr) s += acc[fm][fn][rr];
        s += __shfl_xor(s, 16);
        s += __shfl_xor(s, 32);
        val[fn] = s;
    }

    __syncthreads();   // An/Bq reads done; T8 may overwrite AfBf[0]

    // T8[q][n] fp8 swizzled (16B granules, 8/row): 4 consecutive n per u32
#pragma unroll
    for (int fn = 0; fn < 4; ++fn) {
        const int q  = wq + fn * 16 + la;
        const int fq = FSW(q);
#pragma unroll
        for (int fm = 0; fm < 4; ++fm) {
            const int n0 = wn2 + fm * 16 + (kg << 2);
            const unsigned rv = pk_fp8x4(acc[fm][fn][0], acc[fm][fn][1],
                                         acc[fm][fn][2], acc[fm][fn][3]);
            *(unsigned*)&T8[q * 128 + (((n0 >> 4) ^ fq) << 4) + (n0 & 15)] = rv;
        }
    }
    if (kg == 0) {
#pragma unroll
        for (int fn = 0; fn < 4; ++fn)
            red2[w >> 1][wq + fn * 16 + la] = val[fn];
    }
    __syncthreads();

    if (tid < 128) {
        partial[(size_t)nt * 4096 + (b << 10) + qb + tid] =
            red2[0][tid] + red2[1][tid];
    }

    // gather T8 -> e8 global (64B contiguous per thread, 2 threads/row)
    {
        const int ql = tid >> 1;
        const int h  = tid & 1;
        const int fq = FSW(ql);
        unsigned char* dst = e8 + ((size_t)b << 24) + (size_t)(qb + ql) * NMEM + nb;
#pragma unroll
        for (int k = 0; k < 4; ++k) {
            const int m = h * 4 + k;           // granule 0..7
            u32x4 v = *(const u32x4*)&T8[ql * 128 + ((m ^ fq) << 4)];
            *(u32x4*)(dst + m * 16) = v;
        }
    }
}

// K3: read e8 fp8 [q][n], scale by invsum[q], write p fp32 [n][q] via LDS
// transpose. Block = 64 q x 128 n. grid (16,128,4).
__global__ __launch_bounds__(256)
void k3_big(float* __restrict__ p, const unsigned char* __restrict__ e8,
            const float* __restrict__ invsum)
{
    const int qb = blockIdx.x << 6;
    const int nb = blockIdx.y << 7;
    const int b  = blockIdx.z;

    __shared__ __align__(16) float P[64 * 128];

    const int tid = threadIdx.x;

    {
        const int ql  = tid >> 2;
        const int nc  = (tid & 3) << 5;        // 32 n per thread
        const int fq  = FSW(ql);
        const float inv = invsum[(b << 10) + qb + ql];
        const unsigned char* rowp = e8 + ((size_t)b << 24)
                                       + (size_t)(qb + ql) * NMEM + nb + nc;
#pragma unroll
        for (int k = 0; k < 4; ++k) {
            u32x2 v = *(const u32x2*)(rowp + k * 8);
            f32x2 d0 = __builtin_amdgcn_cvt_pk_f32_fp8(v[0], false);
            f32x2 d1 = __builtin_amdgcn_cvt_pk_f32_fp8(v[0], true);
            f32x2 d2 = __builtin_amdgcn_cvt_pk_f32_fp8(v[1], false);
            f32x2 d3 = __builtin_amdgcn_cvt_pk_f32_fp8(v[1], true);
            float f[8];
            f[0] = d0[0] * inv; f[1] = d0[1] * inv;
            f[2] = d1[0] * inv; f[3] = d1[1] * inv;
            f[4] = d2[0] * inv; f[5] = d2[1] * inv;
            f[6] = d3[0] * inv; f[7] = d3[1] * inv;
            const int gg0 = (nc >> 2) + k * 2;
            *(f32x4*)&P[ql * 128 + (((gg0)     ^ fq) << 2)] = *(f32x4*)&f[0];
            *(f32x4*)&P[ql * 128 + (((gg0 + 1) ^ fq) << 2)] = *(f32x4*)&f[4];
        }
    }
    __syncthreads();

    {
        const int tx  = tid & 15;
        const int tyy = tid >> 4;
        float* pb = p + ((size_t)b << 24);
#pragma unroll
        for (int rr = 0; rr < 2; ++rr) {
            const int gg = tyy + 16 * rr;
            f32x4 v[4];
#pragma unroll
            for (int i = 0; i < 4; ++i) {
                const int ql = tx * 4 + i;
                v[i] = *(const f32x4*)&P[ql * 128 + ((gg ^ FSW(ql)) << 2)];
            }
#pragma unroll
            for (int jj = 0; jj < 4; ++jj) {
                f32x4 o = {v[0][jj], v[1][jj], v[2][jj], v[3][jj]};
                *(f32x4*)(pb + (size_t)(nb + gg * 4 + jj) * QCOL + qb + tx * 4) = o;
            }
        }
    }
}

// ---------------------------------------------------------------------------
// K4 split-K fp8: mem_raw[b][o][q] = sum_n mo8[o][n]*e8[b][q][n], K split x4.
// 128x128 tile, 4 waves each 64x64 (4x4 frags of 16x16x32 fp8), BK=128 bytes.
// XCD grouping: idx&7 keys the (split,b,qt) group -> the 4 ot-blocks sharing
// one e8 B-panel (512KB) land on the same XCD's L2 (R9 FETCH was ~2.7x unique).
// split0 -> out0 raw, 1..3 -> part.
// ---------------------------------------------------------------------------
__global__ __launch_bounds__(256, 2)
void k4_sk8(const unsigned char* __restrict__ mo8,
            const unsigned char* __restrict__ e8,
            float* __restrict__ out0, float* __restrict__ part)
{
    // idx = c + 8*(ot + 4*ghi); group g = ghi*8 + c in [0,128)
    const int idx = blockIdx.x;
    const int c   = idx & 7;
    const int rr_ = idx >> 3;
    const int ot  = rr_ & 3;
    const int g   = ((rr_ >> 2) << 3) | c;   // 0..127
    const int split = g & 3;
    const int b     = (g >> 2) & 3;
    const int qt    = g >> 4;                // 0..7
    const int ob = ot << 7;
    const int qb = qt << 7;
    const int kb = split << 12;              // byte offset

    __shared__ __align__(16) unsigned char As[2][128 * 128];
    __shared__ __align__(16) unsigned char Bs[2][128 * 128];

    const int tid  = threadIdx.x;
    const int lane = tid & 63;
    const int w    = tid >> 6;
    const int wm   = (w >> 1) << 6;   // 0/64 (o)
    const int wn   = (w & 1) << 6;    // 0/64 (q)
    const int la   = lane & 15;
    const int kg   = lane >> 4;

    size_t offA[4], offB[4];
    int lbo[4];
#pragma unroll
    for (int i = 0; i < 4; ++i) {
        const int rb  = (w << 5) + (i << 3);
        const int row = rb + (lane >> 3);
        const int gs  = (lane & 7) ^ FSW(row);
        offA[i] = (size_t)(ob + row) * NMEM + gs * 16;
        offB[i] = (size_t)(qb + row) * NMEM + gs * 16;
        lbo[i]  = rb * 128;
    }
    const unsigned char* e8b = e8 + ((size_t)b << 24);

#define SK_STAGE(BUF, K0)                                                      \
    do {                                                                       \
        _Pragma("unroll")                                                      \
        for (int i = 0; i < 4; ++i) {                                          \
            gl16c(mo8 + offA[i] + (K0), &As[BUF][lbo[i]]);                     \
            gl16c(e8b + offB[i] + (K0), &Bs[BUF][lbo[i]]);                     \
        }                                                                      \
    } while (0)

    int rA[4][4], rB[4][4];
#pragma unroll
    for (int f = 0; f < 4; ++f) {
        const int rowA = wm + f * 16 + la;
        const int rowB = wn + f * 16 + la;
#pragma unroll
        for (int ks = 0; ks < 4; ++ks) {
            const int gg = ks * 2 + (kg >> 1);
            rA[f][ks] = rowA * 128 + ((gg ^ FSW(rowA)) << 4) + ((kg & 1) << 3);
            rB[f][ks] = rowB * 128 + ((gg ^ FSW(rowB)) << 4) + ((kg & 1) << 3);
        }
    }

    f32x4 acc[4][4];
#pragma unroll
    for (int i = 0; i < 4; ++i)
#pragma unroll
        for (int j = 0; j < 4; ++j) acc[i][j] = (f32x4){0.f, 0.f, 0.f, 0.f};

    SK_STAGE(0, kb);
    __syncthreads();

    int cur = 0;
    for (int t = 0; t < 32; ++t) {
        const bool pf = (t + 1) < 32;
        if (pf) SK_STAGE(cur ^ 1, kb + (t + 1) * 128);

#pragma unroll
        for (int ks = 0; ks < 4; ++ks) {
            long af[4], bf[4];
#pragma unroll
            for (int f = 0; f < 4; ++f) {
                af[f] = *(const long*)&As[cur][rA[f][ks]];
                bf[f] = *(const long*)&Bs[cur][rB[f][ks]];
            }
#pragma unroll
            for (int fm = 0; fm < 4; ++fm)
#pragma unroll
                for (int fn = 0; fn < 4; ++fn)
                    acc[fm][fn] = __builtin_amdgcn_mfma_f32_16x16x32_fp8_fp8(
                        af[fm], bf[fn], acc[fm][fn], 0, 0, 0);
        }
        __syncthreads();
        cur ^= 1;
    }

    if (split == 0) {
        float* outb = out0 + ((size_t)b << 20);
#pragma unroll
        for (int fm = 0; fm < 4; ++fm)
#pragma unroll
            for (int fn = 0; fn < 4; ++fn)
#pragma unroll
                for (int rr = 0; rr < 4; ++rr) {
                    const int o = ob + wm + fm * 16 + (kg << 2) + rr;
                    const int q = qb + wn + fn * 16 + la;
                    outb[(size_t)o * 1024 + q] = acc[fm][fn][rr];
                }
    } else {
        float* pp = part + (size_t)(split - 1) * 2097152;
#pragma unroll
        for (int fm = 0; fm < 4; ++fm)
#pragma unroll
            for (int fn = 0; fn < 4; ++fn)
#pragma unroll
                for (int rr = 0; rr < 4; ++rr) {
                    const int o = ob + wm + fm * 16 + (kg << 2) + rr;
                    const int q = qb + wn + fn * 16 + la;
                    pp[(((size_t)(b << 9) + o) << 10) + q] = acc[fm][fn][rr];
                }
    }
#undef SK_STAGE
}

// K56: fused combine + q_out copy. grid 2048 x 256.
__global__ __launch_bounds__(256)
void k56_fin(float* __restrict__ out0, const float* __restrict__ part,
             const float* __restrict__ invsum, const float* __restrict__ qo)
{
    const size_t t = (size_t)blockIdx.x * 256 + threadIdx.x;
    if (t < 524288ull) {
        const size_t v = t << 2;
        const int b = (int)(v >> 19);
        const int q = (int)(v & 1023);
        float* dst = out0 + v + ((size_t)b << 19);
        f32x4 s0 = *(const f32x4*)dst;
        f32x4 s1 = *(const f32x4*)(part + v);
        f32x4 s2 = *(const f32x4*)(part + v + 2097152);
        f32x4 s3 = *(const f32x4*)(part + v + 4194304);
        f32x4 inv = *(const f32x4*)(invsum + (b << 10) + q);
        f32x4 o;
#pragma unroll
        for (int h = 0; h < 4; ++h)
            o[h] = (s0[h] + s1[h] + s2[h] + s3[h]) * inv[h];
        *(f32x4*)dst = o;
        const f32x4 cv = *(const f32x4*)(qo + v);
        *(f32x4*)(out0 + v + ((size_t)(b + 1) << 19)) = cv;
    }
}

// ===========================================================================
// SMALL-WS FALLBACK PATH (R4 pipeline, self-contained)
// ===========================================================================

__global__ __launch_bounds__(256, 2)
void k1_p(const float* __restrict__ mi, const float* __restrict__ qi,
          float* __restrict__ p, float* __restrict__ partial)
{
    const int qb = blockIdx.x << 7;
    const int nb = blockIdx.y << 7;
    const int b  = blockIdx.z;
    const float* __restrict__ qib = qi + (size_t)b * (DE * QCOL);

    __shared__ float As[8][132];
    __shared__ float Bs[8][132];
    __shared__ float red[16][128];

    const int tid = threadIdx.x;
    const int tx  = tid & 15;
    const int ty  = tid >> 4;

    float acc[8][8];
#pragma unroll
    for (int i = 0; i < 8; ++i)
#pragma unroll
        for (int j = 0; j < 8; ++j) acc[i][j] = 0.f;

    const int ld_d = tid >> 5;
    const int ld_n = (tid & 31) << 2;

    for (int k0 = 0; k0 < DE; k0 += 8) {
        float4 av = *(const float4*)(mi  + (size_t)(k0 + ld_d) * NMEM + nb + ld_n);
        float4 bv = *(const float4*)(qib + (size_t)(k0 + ld_d) * QCOL + qb + ld_n);
        *(float4*)&As[ld_d][ld_n] = av;
        *(float4*)&Bs[ld_d][ld_n] = bv;
        __syncthreads();
#pragma unroll
        for (int kk = 0; kk < 8; ++kk) {
            float a[8], bb[8];
            *(float4*)&a[0]  = *(float4*)&As[kk][ty * 8];
            *(float4*)&a[4]  = *(float4*)&As[kk][ty * 8 + 4];
            *(float4*)&bb[0] = *(float4*)&Bs[kk][tx * 8];
            *(float4*)&bb[4] = *(float4*)&Bs[kk][tx * 8 + 4];
#pragma unroll
            for (int i = 0; i < 8; ++i)
#pragma unroll
                for (int j = 0; j < 8; ++j)
                    acc[i][j] += a[i] * bb[j];
        }
        __syncthreads();
    }

    const float scale = 0.08838834764831845f;
    float cs[8];
#pragma unroll
    for (int j = 0; j < 8; ++j) cs[j] = 0.f;
    float* __restrict__ pb = p + ((size_t)b << 24);
#pragma unroll
    for (int i = 0; i < 8; ++i) {
        const int n = nb + ty * 8 + i;
        float e[8];
#pragma unroll
        for (int j = 0; j < 8; ++j) {
            e[j] = __expf(acc[i][j] * scale);
            cs[j] += e[j];
        }
        *(float4*)(pb + ((size_t)n << 10) + qb + tx * 8)     = *(float4*)&e[0];
        *(float4*)(pb + ((size_t)n << 10) + qb + tx * 8 + 4) = *(float4*)&e[4];
    }

#pragma unroll
    for (int j = 0; j < 8; ++j) red[ty][tx * 8 + j] = cs[j];
    __syncthreads();
    if (tid < 128) {
        float s = 0.f;
#pragma unroll
        for (int t = 0; t < 16; ++t) s += red[t][tid];
        partial[(size_t)blockIdx.y * 4096 + (b << 10) + qb + tid] = s;
    }
}

__global__ __launch_bounds__(256)
void k3_small(float* __restrict__ p, const float* __restrict__ invsum)
{
    const size_t stride = (size_t)gridDim.x * blockDim.x;
    for (size_t t = (size_t)blockIdx.x * 256 + threadIdx.x; t < 16777216ull; t += stride) {
        const size_t i = t << 2;
        float4 v = *(float4*)(p + i);
        const int q = (int)(i & 1023);
        const int b = (int)(i >> 24);
        const float4 inv = *(const float4*)(invsum + (b << 10) + q);
        v.x *= inv.x; v.y *= inv.y; v.z *= inv.z; v.w *= inv.w;
        *(float4*)(p + i) = v;
    }
}

__global__ __launch_bounds__(256, 2)
void k4_reg(const float* __restrict__ mo, const float* __restrict__ p,
            float* __restrict__ out0)
{
    const int qb = blockIdx.x << 6;
    const int ob = blockIdx.y << 6;
    const int b  = blockIdx.z;
    const float* __restrict__ pb = p + ((size_t)b << 24);

    __shared__ __align__(16) short As[2][64 * 128];
    __shared__ __align__(16) short Bs[2][64 * 128];

    const int tid  = threadIdx.x;
    const int lane = tid & 63;
    const int w    = tid >> 6;
    const int wm   = (w >> 1) << 5;
    const int wn   = (w & 1) << 5;

    const int aro = tid >> 4;
    const int ak8 = (tid & 15) << 3;
    const int bn8 = (tid >> 4) << 3;
    const int bq4 = (tid & 15) << 2;

    int sA[4], sB[4];
#pragma unroll
    for (int j = 0; j < 4; ++j) {
        const int rlA = aro + 16 * j;
        sA[j] = rlA * 128 + ((((ak8 >> 3) ^ FSW(rlA))) << 3);
        const int rlB = bq4 + j;
        sB[j] = rlB * 128 + ((((bn8 >> 3) ^ FSW(rlB))) << 3);
    }

    const float* __restrict__ gA = mo + (size_t)(ob + aro) * NMEM + ak8;
    const float* __restrict__ gB = pb + (size_t)bn8 * QCOL + qb + bq4;

    f32x4 aA[4][2], aB[8];

#define K4_LOAD(K0)                                                              \
    do {                                                                         \
        _Pragma("unroll")                                                        \
        for (int j = 0; j < 4; ++j) {                                            \
            aA[j][0] = *(const f32x4*)(gA + (size_t)(16 * j) * NMEM + (K0));     \
            aA[j][1] = *(const f32x4*)(gA + (size_t)(16 * j) * NMEM + (K0) + 4); \
        }                                                                        \
        _Pragma("unroll")                                                        \
        for (int i = 0; i < 8; ++i)                                              \
            aB[i] = *(const f32x4*)(gB + ((size_t)(K0) + i) * QCOL);             \
    } while (0)

#define K4_STORE(BUF)                                                            \
    do {                                                                         \
        _Pragma("unroll")                                                        \
        for (int j = 0; j < 4; ++j) {                                            \
            short8v v;                                                           \
            _Pragma("unroll")                                                    \
            for (int h = 0; h < 4; ++h) { v[h] = f2bf(aA[j][0][h]);              \
                                          v[h + 4] = f2bf(aA[j][1][h]); }        \
            *(short8v*)&As[BUF][sA[j]] = v;                                      \
        }                                                                        \
        _Pragma("unroll")                                                        \
        for (int j = 0; j < 4; ++j) {                                            \
            short8v v;                                                           \
            _Pragma("unroll")                                                    \
            for (int i = 0; i < 8; ++i) v[i] = f2bf(aB[i][j]);                   \
            *(short8v*)&Bs[BUF][sB[j]] = v;                                      \
        }                                                                        \
    } while (0)

    f32x4 acc[2][2];
#pragma unroll
    for (int i = 0; i < 2; ++i)
#pragma unroll
        for (int j = 0; j < 2; ++j) acc[i][j] = (f32x4){0.f, 0.f, 0.f, 0.f};

    K4_LOAD(0);
    K4_STORE(0);
    __syncthreads();

    const int la = lane & 15;
    const int kg = lane >> 4;

    int rA[2][4], rB[2][4];
#pragma unroll
    for (int fm = 0; fm < 2; ++fm) {
        const int rowA = wm + la + 16 * fm;
        const int rowB = wn + la + 16 * fm;
#pragma unroll
        for (int s = 0; s < 4; ++s) {
            rA[fm][s] = rowA * 128 + ((((s << 2) + kg) ^ FSW(rowA)) << 3);
            rB[fm][s] = rowB * 128 + ((((s << 2) + kg) ^ FSW(rowB)) << 3);
        }
    }

    int cur = 0;
    for (int t = 0; t < NMEM / 128; ++t) {
        const bool pf = (t + 1) < NMEM / 128;
        if (pf) K4_LOAD((t + 1) * 128);

#pragma unroll
        for (int s = 0; s < 4; ++s) {
            short8v a0 = *(const short8v*)&As[cur][rA[0][s]];
            short8v a1 = *(const short8v*)&As[cur][rA[1][s]];
            short8v b0 = *(const short8v*)&Bs[cur][rB[0][s]];
            short8v b1 = *(const short8v*)&Bs[cur][rB[1][s]];
            acc[0][0] = __builtin_amdgcn_mfma_f32_16x16x32_bf16(a0, b0, acc[0][0], 0, 0, 0);
            acc[0][1] = __builtin_amdgcn_mfma_f32_16x16x32_bf16(a0, b1, acc[0][1], 0, 0, 0);
            acc[1][0] = __builtin_amdgcn_mfma_f32_16x16x32_bf16(a1, b0, acc[1][0], 0, 0, 0);
            acc[1][1] = __builtin_amdgcn_mfma_f32_16x16x32_bf16(a1, b1, acc[1][1], 0, 0, 0);
        }

        if (pf) K4_STORE(cur ^ 1);
        __syncthreads();
        cur ^= 1;
    }

    const int orow = ob + wm + (kg << 2);
    const int qcol = qb + wn + la;
    float* __restrict__ outb = out0 + ((size_t)b << 20);
#pragma unroll
    for (int fm = 0; fm < 2; ++fm)
#pragma unroll
        for (int fn = 0; fn < 2; ++fn)
#pragma unroll
            for (int r = 0; r < 4; ++r)
                outb[(size_t)(orow + 16 * fm + r) * 1024 + qcol + 16 * fn] =
                    acc[fm][fn][r];
#undef K4_LOAD
#undef K4_STORE
}

__global__ __launch_bounds__(256)
void k5_copy(const float* __restrict__ qo, float* __restrict__ out0)
{
    const size_t t = (size_t)blockIdx.x * 256 + threadIdx.x;
    if (t < 524288ull) {
        const size_t i = t << 2;
        const size_t b = i >> 19;
        const float4 v = *(const float4*)(qo + i);
        *(float4*)(out0 + i + ((b + 1) << 19)) = v;
    }
}

// ===========================================================================
// SHARED
// ===========================================================================

__global__ __launch_bounds__(256)
void k2b_red(const float* __restrict__ partial, float* __restrict__ invsum)
{
    __shared__ float red[8][32];
    const int col = blockIdx.x * 32 + (threadIdx.x & 31);
    const int g   = threadIdx.x >> 5;
    float s = 0.f;
#pragma unroll
    for (int r = 0; r < 16; ++r)
        s += partial[(size_t)(g * 16 + r) * 4096 + col];
    red[g][threadIdx.x & 31] = s;
    __syncthreads();
    if (threadIdx.x < 32) {
        float t = 0.f;
#pragma unroll
        for (int g2 = 0; g2 < 8; ++g2) t += red[g2][threadIdx.x];
        invsum[col] = 1.0f / t;
    }
}

extern "C" void kernel_launch(void* const* d_in, const int* in_sizes, int n_in,
                              void* d_out, int out_size, void* d_ws, size_t ws_size,
                              hipStream_t stream)
{
    const float* m_in  = (const float*)d_in[0];
    const float* m_out = (const float*)d_in[1];
    const float* q_in  = (const float*)d_in[2];
    const float* q_out = (const float*)d_in[3];

    float* out0 = (float*)d_out;              // 4,194,304 floats
    float* p    = out0 + 4194304;             // 67,108,864 floats

    unsigned char* e8  = (unsigned char*)d_ws;        // 64MB fp8
    unsigned char* mo8 = e8 + 67108864;               // 8MB fp8
    float* wpart   = (float*)(e8 + 75497472);         // 3 x 2M fp32 partials
    float* partialW= (float*)(e8 + 100663296);        // [128][4][1024] fp32
    float* invsumW = (float*)(e8 + 102760448);        // [4][1024] fp32

    // fallback scratch in out0's q_out-copy regions (overwritten by k5):
    float* partialF = out0 + 524288;
    float* invsumF  = out0 + 1048576 + 524288;

    const size_t need_big = 176160768ull;

    if (ws_size >= need_big) {
        k1_mfma<<<dim3(5120),       256, 0, stream>>>(m_in, q_in, m_out,
                                                      e8, mo8, partialW);
        k2b_red<<<dim3(128),        256, 0, stream>>>(partialW, invsumW);
        k3_big <<<dim3(16, 128, 4), 256, 0, stream>>>(p, e8, invsumW);
        k4_sk8 <<<dim3(512),        256, 0, stream>>>(mo8, e8, out0, wpart);
        k56_fin<<<dim3(2048),       256, 0, stream>>>(out0, wpart, invsumW, q_out);
    } else {
        k1_p    <<<dim3(8, 128, 4), 256, 0, stream>>>(m_in, q_in, p, partialF);
        k2b_red <<<dim3(128),       256, 0, stream>>>(partialF, invsumF);
        k3_small<<<dim3(2048),      256, 0, stream>>>(p, invsumF);
        k4_reg  <<<dim3(16, 8, 4),  256, 0, stream>>>(m_out, p, out0);
        k5_copy <<<dim3(2048),      256, 0, stream>>>(q_out, out0);
    }
}

// Round 14
// 192.451 us; speedup vs baseline: 1.0310x; 1.0310x over previous
//
#include <hip/hip_runtime.h>
#include <hip/hip_bf16.h>
#include <cstddef>

// m_in  raw-viewed as mi [128][16384]   fp32
// m_out raw-viewed as mo [512][16384]   fp32
// q_in  = qi [4][128][1024]             fp32
// q_out = qo [4][512][1024]             fp32
// out0  = mem_out [4][1024][1024]  (ch 0..511 = mem, ch 512..1023 = q_out copy)
// out1  = p [4][16384][1024] softmax over the 16384 axis
//
// ws layout (big path, gate ws_size >= 176160768):
//   [0, 64MB)        e8  fp8 e4m3 [4][1024][16384]
//   [64MB, 72MB)     mo8 fp8 e4m3 [512][16384]
//   [72MB, 96MB)     split-K partials: 3 x 2M fp32
//   [96MB, 98MB)     partial colsums [128][4][1024] fp32
//   [98MB, +16KB)    invsum [4][1024] fp32

#define DE   128
#define DO   512
#define NMEM 16384
#define QCOL 1024

typedef __attribute__((ext_vector_type(8))) short    short8v;
typedef __attribute__((ext_vector_type(8))) _Float16 half8v;
typedef __attribute__((ext_vector_type(4))) float    f32x4;
typedef __attribute__((ext_vector_type(2))) float    f32x2;
typedef __attribute__((ext_vector_type(2))) unsigned u32x2;
typedef __attribute__((ext_vector_type(4))) unsigned u32x4;

__device__ __forceinline__ short f2bf(float x) {
    union { __hip_bfloat16 h; short s; } u;
    u.h = __float2bfloat16(x);
    return u.s;
}

// pack 4 f32 -> 4 fp8(e4m3) in a u32
__device__ __forceinline__ unsigned pk_fp8x4(float f0, float f1, float f2, float f3) {
    unsigned r = __builtin_amdgcn_cvt_pk_fp8_f32(f0, f1, 0, false);
    r = __builtin_amdgcn_cvt_pk_fp8_f32(f2, f3, r, true);
    return r;
}

// bank-balancing XOR swizzle (granule-level), bijective per 8-row stripe
#define FSW(r) ((((r) >> 3) ^ (r)) & 7)

__device__ __forceinline__ void gl16c(const unsigned char* g, unsigned char* l) {
    __builtin_amdgcn_global_load_lds(
        (const __attribute__((address_space(1))) void*)g,
        (__attribute__((address_space(3))) void*)l, 16, 0, 0);
}

// ===========================================================================
// BIG-WS PATH (fp8)
// ===========================================================================

// K1: C[n][q] = sum_d mi[d][n]*qi[d][q] via f16 MFMA, e=exp -> e8 fp8 [b][q][n]
// + per-128n-tile column sums. Block 128q x 128n, K=128 one-shot.
// Flat grid 4096, XCD-grouped: bid%8 keys (nt,b)-group so the 8 qt-blocks
// sharing an mi tile land on one XCD.
__global__ __launch_bounds__(256, 2)
void k1_mfma(const float* __restrict__ mi, const float* __restrict__ qi,
             unsigned char* __restrict__ e8, float* __restrict__ partial)
{
    // decode XCD-grouped flat id: bid = c + 8*(qt + 8*ghi); g = ghi*8+c
    const int bid = blockIdx.x;
    const int c   = bid & 7;
    const int r   = bid >> 3;
    const int qt  = r & 7;
    const int g   = ((r >> 3) << 3) | c;   // 0..511
    const int nt  = g & 127;
    const int b   = g >> 7;
    const int qb  = qt << 7;
    const int nb  = nt << 7;

    __shared__ __align__(16) short AfBf[2][128 * 128]; // f16 as shorts
    __shared__ float red2[2][128];

    short* Bq = AfBf[0];   // [q][d] swizzled (B operand)
    short* An = AfBf[1];   // [n][d] swizzled (A operand)
    unsigned char* T8 = (unsigned char*)AfBf[0];  // reused: [q][n] fp8 swizzled

    const int tid  = threadIdx.x;
    const int lane = tid & 63;
    const int w    = tid >> 6;
    const int wn2  = (w >> 1) << 6;   // n-half 0/64
    const int wq   = (w & 1) << 6;    // q-half 0/64
    const int la   = lane & 15;
    const int kg   = lane >> 4;

    // staging: thread covers 8 d-rows x (2 x 4 cols), reg-transpose, swizzled
    {
        const int d8 = (tid >> 4) << 3;       // 0..120
        const int c4 = (tid & 15) << 2;       // 0..60
        const float* qib = qi + (size_t)b * (DE * QCOL) + (size_t)d8 * QCOL + qb;
        const float* mib = mi + (size_t)d8 * NMEM + nb;
#pragma unroll
        for (int half = 0; half < 2; ++half) {
            const int cc = c4 + (half << 6);  // 0..124
            f32x4 qv[8], mv[8];
#pragma unroll
            for (int i = 0; i < 8; ++i) {
                qv[i] = *(const f32x4*)(qib + (size_t)i * QCOL + cc);
                mv[i] = *(const f32x4*)(mib + (size_t)i * NMEM + cc);
            }
#pragma unroll
            for (int j = 0; j < 4; ++j) {
                const int row = cc + j;
                const int off = row * 128 + ((((d8 >> 3) ^ FSW(row))) << 3);
                half8v av, bv;
#pragma unroll
                for (int i = 0; i < 8; ++i) {
                    av[i] = (_Float16)qv[i][j];
                    bv[i] = (_Float16)mv[i][j];
                }
                *(half8v*)&Bq[off] = av;
                *(half8v*)&An[off] = bv;
            }
        }
    }
    __syncthreads();

    // MFMA: acc[fm][fn]: row n = wn2+fm*16+(kg<<2)+r ; col q = wq+fn*16+la
    f32x4 acc[4][4];
#pragma unroll
    for (int i = 0; i < 4; ++i)
#pragma unroll
        for (int j = 0; j < 4; ++j) acc[i][j] = (f32x4){0.f, 0.f, 0.f, 0.f};

#pragma unroll
    for (int ks = 0; ks < 4; ++ks) {
        half8v af[4], bf[4];
#pragma unroll
        for (int f = 0; f < 4; ++f) {
            const int ra = wn2 + f * 16 + la;   // A rows: n
            const int rb = wq  + f * 16 + la;   // B rows: q
            af[f] = *(const half8v*)&An[ra * 128 + ((((ks << 2) + kg) ^ FSW(ra)) << 3)];
            bf[f] = *(const half8v*)&Bq[rb * 128 + ((((ks << 2) + kg) ^ FSW(rb)) << 3)];
        }
#pragma unroll
        for (int fm = 0; fm < 4; ++fm)
#pragma unroll
            for (int fn = 0; fn < 4; ++fn)
                acc[fm][fn] = __builtin_amdgcn_mfma_f32_16x16x32_f16(
                    af[fm], bf[fn], acc[fm][fn], 0, 0, 0);
    }

    const float scale = 0.08838834764831845f; // 1/sqrt(128)
#pragma unroll
    for (int fm = 0; fm < 4; ++fm)
#pragma unroll
        for (int fn = 0; fn < 4; ++fn)
#pragma unroll
            for (int rr = 0; rr < 4; ++rr)
                acc[fm][fn][rr] = __expf(acc[fm][fn][rr] * scale);

    // colsum over n per q-col
    float val[4];
#pragma unroll
    for (int fn = 0; fn < 4; ++fn) {
        float s = 0.f;
#pragma unroll
        for (int fm = 0; fm < 4; ++fm)
#pragma unroll
            for (int rr = 0; rr < 4; ++rr) s += acc[fm][fn][rr];
        s += __shfl_xor(s, 16);
        s += __shfl_xor(s, 32);
        val[fn] = s;
    }

    __syncthreads();   // An/Bq reads done; T8 may overwrite AfBf[0]

    // T8[q][n] fp8 swizzled (16B granules, 8/row): 4 consecutive n per u32
#pragma unroll
    for (int fn = 0; fn < 4; ++fn) {
        const int q  = wq + fn * 16 + la;
        const int fq = FSW(q);
#pragma unroll
        for (int fm = 0; fm < 4; ++fm) {
            const int n0 = wn2 + fm * 16 + (kg << 2);
            const unsigned rv = pk_fp8x4(acc[fm][fn][0], acc[fm][fn][1],
                                         acc[fm][fn][2], acc[fm][fn][3]);
            *(unsigned*)&T8[q * 128 + (((n0 >> 4) ^ fq) << 4) + (n0 & 15)] = rv;
        }
    }
    if (kg == 0) {
#pragma unroll
        for (int fn = 0; fn < 4; ++fn)
            red2[w >> 1][wq + fn * 16 + la] = val[fn];
    }
    __syncthreads();

    if (tid < 128) {
        partial[(size_t)nt * 4096 + (b << 10) + qb + tid] =
            red2[0][tid] + red2[1][tid];
    }

    // gather T8 -> e8 global (64B contiguous per thread, 2 threads/row)
    {
        const int ql = tid >> 1;
        const int h  = tid & 1;
        const int fq = FSW(ql);
        unsigned char* dst = e8 + ((size_t)b << 24) + (size_t)(qb + ql) * NMEM + nb;
#pragma unroll
        for (int k = 0; k < 4; ++k) {
            const int m = h * 4 + k;           // granule 0..7
            u32x4 v = *(const u32x4*)&T8[ql * 128 + ((m ^ fq) << 4)];
            *(u32x4*)(dst + m * 16) = v;
        }
    }
}

// K3: read e8 fp8 [q][n], scale by invsum[q], write p fp32 [n][q] via LDS
// transpose. Block = 64 q x 128 n. grid (16,128,4).
__global__ __launch_bounds__(256)
void k3_big(float* __restrict__ p, const unsigned char* __restrict__ e8,
            const float* __restrict__ invsum)
{
    const int qb = blockIdx.x << 6;
    const int nb = blockIdx.y << 7;
    const int b  = blockIdx.z;

    __shared__ __align__(16) float P[64 * 128];

    const int tid = threadIdx.x;

    {
        const int ql  = tid >> 2;
        const int nc  = (tid & 3) << 5;        // 32 n per thread
        const int fq  = FSW(ql);
        const float inv = invsum[(b << 10) + qb + ql];
        const unsigned char* rowp = e8 + ((size_t)b << 24)
                                       + (size_t)(qb + ql) * NMEM + nb + nc;
#pragma unroll
        for (int k = 0; k < 4; ++k) {
            u32x2 v = *(const u32x2*)(rowp + k * 8);
            f32x2 d0 = __builtin_amdgcn_cvt_pk_f32_fp8(v[0], false);
            f32x2 d1 = __builtin_amdgcn_cvt_pk_f32_fp8(v[0], true);
            f32x2 d2 = __builtin_amdgcn_cvt_pk_f32_fp8(v[1], false);
            f32x2 d3 = __builtin_amdgcn_cvt_pk_f32_fp8(v[1], true);
            float f[8];
            f[0] = d0[0] * inv; f[1] = d0[1] * inv;
            f[2] = d1[0] * inv; f[3] = d1[1] * inv;
            f[4] = d2[0] * inv; f[5] = d2[1] * inv;
            f[6] = d3[0] * inv; f[7] = d3[1] * inv;
            const int gg0 = (nc >> 2) + k * 2;
            *(f32x4*)&P[ql * 128 + (((gg0)     ^ fq) << 2)] = *(f32x4*)&f[0];
            *(f32x4*)&P[ql * 128 + (((gg0 + 1) ^ fq) << 2)] = *(f32x4*)&f[4];
        }
    }
    __syncthreads();

    {
        const int tx  = tid & 15;
        const int tyy = tid >> 4;
        float* pb = p + ((size_t)b << 24);
#pragma unroll
        for (int rr = 0; rr < 2; ++rr) {
            const int gg = tyy + 16 * rr;
            f32x4 v[4];
#pragma unroll
            for (int i = 0; i < 4; ++i) {
                const int ql = tx * 4 + i;
                v[i] = *(const f32x4*)&P[ql * 128 + ((gg ^ FSW(ql)) << 2)];
            }
#pragma unroll
            for (int jj = 0; jj < 4; ++jj) {
                f32x4 o = {v[0][jj], v[1][jj], v[2][jj], v[3][jj]};
                *(f32x4*)(pb + (size_t)(nb + gg * 4 + jj) * QCOL + qb + tx * 4) = o;
            }
        }
    }
}

// conv8: mo fp32 [512][16384] -> mo8 fp8. grid 1024 x 256 thr x 4 units.
__global__ __launch_bounds__(256)
void conv8(const float* __restrict__ mo, unsigned char* __restrict__ mo8)
{
    const size_t u = (size_t)blockIdx.x * 256 + threadIdx.x;  // 0..262143
#pragma unroll
    for (int r = 0; r < 4; ++r) {
        const size_t i = (u + (size_t)r * 262144) << 3;       // float index
        f32x4 a = *(const f32x4*)(mo + i);
        f32x4 c = *(const f32x4*)(mo + i + 4);
        u32x2 v;
        v[0] = pk_fp8x4(a[0], a[1], a[2], a[3]);
        v[1] = pk_fp8x4(c[0], c[1], c[2], c[3]);
        *(u32x2*)(mo8 + i) = v;
    }
}

// ---------------------------------------------------------------------------
// K4 split-K fp8: mem_raw[b][o][q] = sum_n mo8[o][n]*e8[b][q][n], K split x4.
// 128x128 tile, 4 waves each 64x64 (4x4 frags of 16x16x32 fp8), BK=128 bytes.
// gl_lds staging, pre-swizzled global src, linear LDS dest, swizzled b64
// frag reads. split0 -> out0 raw, 1..3 -> part. grid 512 XCD-swizzled.
// ---------------------------------------------------------------------------
__global__ __launch_bounds__(256, 2)
void k4_sk8(const unsigned char* __restrict__ mo8,
            const unsigned char* __restrict__ e8,
            float* __restrict__ out0, float* __restrict__ part)
{
    const int sw    = ((blockIdx.x & 7) << 6) | (blockIdx.x >> 3);
    const int split = sw >> 7;          // 0..3
    const int tile  = sw & 127;
    const int b  = tile >> 5;
    const int ot = (tile >> 3) & 3;
    const int qt = tile & 7;
    const int ob = ot << 7;
    const int qb = qt << 7;
    const int kb = split << 12;         // byte offset

    __shared__ __align__(16) unsigned char As[2][128 * 128];
    __shared__ __align__(16) unsigned char Bs[2][128 * 128];

    const int tid  = threadIdx.x;
    const int lane = tid & 63;
    const int w    = tid >> 6;
    const int wm   = (w >> 1) << 6;   // 0/64 (o)
    const int wn   = (w & 1) << 6;    // 0/64 (q)
    const int la   = lane & 15;
    const int kg   = lane >> 4;

    size_t offA[4], offB[4];
    int lbo[4];
#pragma unroll
    for (int i = 0; i < 4; ++i) {
        const int rb  = (w << 5) + (i << 3);
        const int row = rb + (lane >> 3);
        const int gs  = (lane & 7) ^ FSW(row);
        offA[i] = (size_t)(ob + row) * NMEM + gs * 16;
        offB[i] = (size_t)(qb + row) * NMEM + gs * 16;
        lbo[i]  = rb * 128;
    }
    const unsigned char* e8b = e8 + ((size_t)b << 24);

#define SK_STAGE(BUF, K0)                                                      \
    do {                                                                       \
        _Pragma("unroll")                                                      \
        for (int i = 0; i < 4; ++i) {                                          \
            gl16c(mo8 + offA[i] + (K0), &As[BUF][lbo[i]]);                     \
            gl16c(e8b + offB[i] + (K0), &Bs[BUF][lbo[i]]);                     \
        }                                                                      \
    } while (0)

    int rA[4][4], rB[4][4];
#pragma unroll
    for (int f = 0; f < 4; ++f) {
        const int rowA = wm + f * 16 + la;
        const int rowB = wn + f * 16 + la;
#pragma unroll
        for (int ks = 0; ks < 4; ++ks) {
            const int gg = ks * 2 + (kg >> 1);
            rA[f][ks] = rowA * 128 + ((gg ^ FSW(rowA)) << 4) + ((kg & 1) << 3);
            rB[f][ks] = rowB * 128 + ((gg ^ FSW(rowB)) << 4) + ((kg & 1) << 3);
        }
    }

    f32x4 acc[4][4];
#pragma unroll
    for (int i = 0; i < 4; ++i)
#pragma unroll
        for (int j = 0; j < 4; ++j) acc[i][j] = (f32x4){0.f, 0.f, 0.f, 0.f};

    SK_STAGE(0, kb);
    __syncthreads();

    int cur = 0;
    for (int t = 0; t < 32; ++t) {
        const bool pf = (t + 1) < 32;
        if (pf) SK_STAGE(cur ^ 1, kb + (t + 1) * 128);

#pragma unroll
        for (int ks = 0; ks < 4; ++ks) {
            long af[4], bf[4];
#pragma unroll
            for (int f = 0; f < 4; ++f) {
                af[f] = *(const long*)&As[cur][rA[f][ks]];
                bf[f] = *(const long*)&Bs[cur][rB[f][ks]];
            }
#pragma unroll
            for (int fm = 0; fm < 4; ++fm)
#pragma unroll
                for (int fn = 0; fn < 4; ++fn)
                    acc[fm][fn] = __builtin_amdgcn_mfma_f32_16x16x32_fp8_fp8(
                        af[fm], bf[fn], acc[fm][fn], 0, 0, 0);
        }
        __syncthreads();
        cur ^= 1;
    }

    if (split == 0) {
        float* outb = out0 + ((size_t)b << 20);
#pragma unroll
        for (int fm = 0; fm < 4; ++fm)
#pragma unroll
            for (int fn = 0; fn < 4; ++fn)
#pragma unroll
                for (int rr = 0; rr < 4; ++rr) {
                    const int o = ob + wm + fm * 16 + (kg << 2) + rr;
                    const int q = qb + wn + fn * 16 + la;
                    outb[(size_t)o * 1024 + q] = acc[fm][fn][rr];
                }
    } else {
        float* pp = part + (size_t)(split - 1) * 2097152;
#pragma unroll
        for (int fm = 0; fm < 4; ++fm)
#pragma unroll
            for (int fn = 0; fn < 4; ++fn)
#pragma unroll
                for (int rr = 0; rr < 4; ++rr) {
                    const int o = ob + wm + fm * 16 + (kg << 2) + rr;
                    const int q = qb + wn + fn * 16 + la;
                    pp[(((size_t)(b << 9) + o) << 10) + q] = acc[fm][fn][rr];
                }
    }
#undef SK_STAGE
}

// K56: fused combine + q_out copy (invsum lives in ws -> no aliasing hazard).
// grid 2048 x 256.
__global__ __launch_bounds__(256)
void k56_fin(float* __restrict__ out0, const float* __restrict__ part,
             const float* __restrict__ invsum, const float* __restrict__ qo)
{
    const size_t t = (size_t)blockIdx.x * 256 + threadIdx.x;
    if (t < 524288ull) {
        const size_t v = t << 2;
        const int b = (int)(v >> 19);
        const int q = (int)(v & 1023);
        float* dst = out0 + v + ((size_t)b << 19);
        f32x4 s0 = *(const f32x4*)dst;
        f32x4 s1 = *(const f32x4*)(part + v);
        f32x4 s2 = *(const f32x4*)(part + v + 2097152);
        f32x4 s3 = *(const f32x4*)(part + v + 4194304);
        f32x4 inv = *(const f32x4*)(invsum + (b << 10) + q);
        f32x4 o;
#pragma unroll
        for (int h = 0; h < 4; ++h)
            o[h] = (s0[h] + s1[h] + s2[h] + s3[h]) * inv[h];
        *(f32x4*)dst = o;
        const f32x4 cv = *(const f32x4*)(qo + v);
        *(f32x4*)(out0 + v + ((size_t)(b + 1) << 19)) = cv;
    }
}

// ===========================================================================
// SMALL-WS FALLBACK PATH (R4 pipeline, self-contained)
// ===========================================================================

__global__ __launch_bounds__(256, 2)
void k1_p(const float* __restrict__ mi, const float* __restrict__ qi,
          float* __restrict__ p, float* __restrict__ partial)
{
    const int qb = blockIdx.x << 7;
    const int nb = blockIdx.y << 7;
    const int b  = blockIdx.z;
    const float* __restrict__ qib = qi + (size_t)b * (DE * QCOL);

    __shared__ float As[8][132];
    __shared__ float Bs[8][132];
    __shared__ float red[16][128];

    const int tid = threadIdx.x;
    const int tx  = tid & 15;
    const int ty  = tid >> 4;

    float acc[8][8];
#pragma unroll
    for (int i = 0; i < 8; ++i)
#pragma unroll
        for (int j = 0; j < 8; ++j) acc[i][j] = 0.f;

    const int ld_d = tid >> 5;
    const int ld_n = (tid & 31) << 2;

    for (int k0 = 0; k0 < DE; k0 += 8) {
        float4 av = *(const float4*)(mi  + (size_t)(k0 + ld_d) * NMEM + nb + ld_n);
        float4 bv = *(const float4*)(qib + (size_t)(k0 + ld_d) * QCOL + qb + ld_n);
        *(float4*)&As[ld_d][ld_n] = av;
        *(float4*)&Bs[ld_d][ld_n] = bv;
        __syncthreads();
#pragma unroll
        for (int kk = 0; kk < 8; ++kk) {
            float a[8], bb[8];
            *(float4*)&a[0]  = *(float4*)&As[kk][ty * 8];
            *(float4*)&a[4]  = *(float4*)&As[kk][ty * 8 + 4];
            *(float4*)&bb[0] = *(float4*)&Bs[kk][tx * 8];
            *(float4*)&bb[4] = *(float4*)&Bs[kk][tx * 8 + 4];
#pragma unroll
            for (int i = 0; i < 8; ++i)
#pragma unroll
                for (int j = 0; j < 8; ++j)
                    acc[i][j] += a[i] * bb[j];
        }
        __syncthreads();
    }

    const float scale = 0.08838834764831845f;
    float cs[8];
#pragma unroll
    for (int j = 0; j < 8; ++j) cs[j] = 0.f;
    float* __restrict__ pb = p + ((size_t)b << 24);
#pragma unroll
    for (int i = 0; i < 8; ++i) {
        const int n = nb + ty * 8 + i;
        float e[8];
#pragma unroll
        for (int j = 0; j < 8; ++j) {
            e[j] = __expf(acc[i][j] * scale);
            cs[j] += e[j];
        }
        *(float4*)(pb + ((size_t)n << 10) + qb + tx * 8)     = *(float4*)&e[0];
        *(float4*)(pb + ((size_t)n << 10) + qb + tx * 8 + 4) = *(float4*)&e[4];
    }

#pragma unroll
    for (int j = 0; j < 8; ++j) red[ty][tx * 8 + j] = cs[j];
    __syncthreads();
    if (tid < 128) {
        float s = 0.f;
#pragma unroll
        for (int t = 0; t < 16; ++t) s += red[t][tid];
        partial[(size_t)blockIdx.y * 4096 + (b << 10) + qb + tid] = s;
    }
}

__global__ __launch_bounds__(256)
void k3_small(float* __restrict__ p, const float* __restrict__ invsum)
{
    const size_t stride = (size_t)gridDim.x * blockDim.x;
    for (size_t t = (size_t)blockIdx.x * 256 + threadIdx.x; t < 16777216ull; t += stride) {
        const size_t i = t << 2;
        float4 v = *(float4*)(p + i);
        const int q = (int)(i & 1023);
        const int b = (int)(i >> 24);
        const float4 inv = *(const float4*)(invsum + (b << 10) + q);
        v.x *= inv.x; v.y *= inv.y; v.z *= inv.z; v.w *= inv.w;
        *(float4*)(p + i) = v;
    }
}

__global__ __launch_bounds__(256, 2)
void k4_reg(const float* __restrict__ mo, const float* __restrict__ p,
            float* __restrict__ out0)
{
    const int qb = blockIdx.x << 6;
    const int ob = blockIdx.y << 6;
    const int b  = blockIdx.z;
    const float* __restrict__ pb = p + ((size_t)b << 24);

    __shared__ __align__(16) short As[2][64 * 128];
    __shared__ __align__(16) short Bs[2][64 * 128];

    const int tid  = threadIdx.x;
    const int lane = tid & 63;
    const int w    = tid >> 6;
    const int wm   = (w >> 1) << 5;
    const int wn   = (w & 1) << 5;

    const int aro = tid >> 4;
    const int ak8 = (tid & 15) << 3;
    const int bn8 = (tid >> 4) << 3;
    const int bq4 = (tid & 15) << 2;

    int sA[4], sB[4];
#pragma unroll
    for (int j = 0; j < 4; ++j) {
        const int rlA = aro + 16 * j;
        sA[j] = rlA * 128 + ((((ak8 >> 3) ^ FSW(rlA))) << 3);
        const int rlB = bq4 + j;
        sB[j] = rlB * 128 + ((((bn8 >> 3) ^ FSW(rlB))) << 3);
    }

    const float* __restrict__ gA = mo + (size_t)(ob + aro) * NMEM + ak8;
    const float* __restrict__ gB = pb + (size_t)bn8 * QCOL + qb + bq4;

    f32x4 aA[4][2], aB[8];

#define K4_LOAD(K0)                                                              \
    do {                                                                         \
        _Pragma("unroll")                                                        \
        for (int j = 0; j < 4; ++j) {                                            \
            aA[j][0] = *(const f32x4*)(gA + (size_t)(16 * j) * NMEM + (K0));     \
            aA[j][1] = *(const f32x4*)(gA + (size_t)(16 * j) * NMEM + (K0) + 4); \
        }                                                                        \
        _Pragma("unroll")                                                        \
        for (int i = 0; i < 8; ++i)                                              \
            aB[i] = *(const f32x4*)(gB + ((size_t)(K0) + i) * QCOL);             \
    } while (0)

#define K4_STORE(BUF)                                                            \
    do {                                                                         \
        _Pragma("unroll")                                                        \
        for (int j = 0; j < 4; ++j) {                                            \
            short8v v;                                                           \
            _Pragma("unroll")                                                    \
            for (int h = 0; h < 4; ++h) { v[h] = f2bf(aA[j][0][h]);              \
                                          v[h + 4] = f2bf(aA[j][1][h]); }        \
            *(short8v*)&As[BUF][sA[j]] = v;                                      \
        }                                                                        \
        _Pragma("unroll")                                                        \
        for (int j = 0; j < 4; ++j) {                                            \
            short8v v;                                                           \
            _Pragma("unroll")                                                    \
            for (int i = 0; i < 8; ++i) v[i] = f2bf(aB[i][j]);                   \
            *(short8v*)&Bs[BUF][sB[j]] = v;                                      \
        }                                                                        \
    } while (0)

    f32x4 acc[2][2];
#pragma unroll
    for (int i = 0; i < 2; ++i)
#pragma unroll
        for (int j = 0; j < 2; ++j) acc[i][j] = (f32x4){0.f, 0.f, 0.f, 0.f};

    K4_LOAD(0);
    K4_STORE(0);
    __syncthreads();

    const int la = lane & 15;
    const int kg = lane >> 4;

    int rA[2][4], rB[2][4];
#pragma unroll
    for (int fm = 0; fm < 2; ++fm) {
        const int rowA = wm + la + 16 * fm;
        const int rowB = wn + la + 16 * fm;
#pragma unroll
        for (int s = 0; s < 4; ++s) {
            rA[fm][s] = rowA * 128 + ((((s << 2) + kg) ^ FSW(rowA)) << 3);
            rB[fm][s] = rowB * 128 + ((((s << 2) + kg) ^ FSW(rowB)) << 3);
        }
    }

    int cur = 0;
    for (int t = 0; t < NMEM / 128; ++t) {
        const bool pf = (t + 1) < NMEM / 128;
        if (pf) K4_LOAD((t + 1) * 128);

#pragma unroll
        for (int s = 0; s < 4; ++s) {
            short8v a0 = *(const short8v*)&As[cur][rA[0][s]];
            short8v a1 = *(const short8v*)&As[cur][rA[1][s]];
            short8v b0 = *(const short8v*)&Bs[cur][rB[0][s]];
            short8v b1 = *(const short8v*)&Bs[cur][rB[1][s]];
            acc[0][0] = __builtin_amdgcn_mfma_f32_16x16x32_bf16(a0, b0, acc[0][0], 0, 0, 0);
            acc[0][1] = __builtin_amdgcn_mfma_f32_16x16x32_bf16(a0, b1, acc[0][1], 0, 0, 0);
            acc[1][0] = __builtin_amdgcn_mfma_f32_16x16x32_bf16(a1, b0, acc[1][0], 0, 0, 0);
            acc[1][1] = __builtin_amdgcn_mfma_f32_16x16x32_bf16(a1, b1, acc[1][1], 0, 0, 0);
        }

        if (pf) K4_STORE(cur ^ 1);
        __syncthreads();
        cur ^= 1;
    }

    const int orow = ob + wm + (kg << 2);
    const int qcol = qb + wn + la;
    float* __restrict__ outb = out0 + ((size_t)b << 20);
#pragma unroll
    for (int fm = 0; fm < 2; ++fm)
#pragma unroll
        for (int fn = 0; fn < 2; ++fn)
#pragma unroll
            for (int r = 0; r < 4; ++r)
                outb[(size_t)(orow + 16 * fm + r) * 1024 + qcol + 16 * fn] =
                    acc[fm][fn][r];
#undef K4_LOAD
#undef K4_STORE
}

__global__ __launch_bounds__(256)
void k5_copy(const float* __restrict__ qo, float* __restrict__ out0)
{
    const size_t t = (size_t)blockIdx.x * 256 + threadIdx.x;
    if (t < 524288ull) {
        const size_t i = t << 2;
        const size_t b = i >> 19;
        const float4 v = *(const float4*)(qo + i);
        *(float4*)(out0 + i + ((b + 1) << 19)) = v;
    }
}

// ===========================================================================
// SHARED
// ===========================================================================

__global__ __launch_bounds__(256)
void k2b_red(const float* __restrict__ partial, float* __restrict__ invsum)
{
    __shared__ float red[8][32];
    const int col = blockIdx.x * 32 + (threadIdx.x & 31);
    const int g   = threadIdx.x >> 5;
    float s = 0.f;
#pragma unroll
    for (int r = 0; r < 16; ++r)
        s += partial[(size_t)(g * 16 + r) * 4096 + col];
    red[g][threadIdx.x & 31] = s;
    __syncthreads();
    if (threadIdx.x < 32) {
        float t = 0.f;
#pragma unroll
        for (int g2 = 0; g2 < 8; ++g2) t += red[g2][threadIdx.x];
        invsum[col] = 1.0f / t;
    }
}

extern "C" void kernel_launch(void* const* d_in, const int* in_sizes, int n_in,
                              void* d_out, int out_size, void* d_ws, size_t ws_size,
                              hipStream_t stream)
{
    const float* m_in  = (const float*)d_in[0];
    const float* m_out = (const float*)d_in[1];
    const float* q_in  = (const float*)d_in[2];
    const float* q_out = (const float*)d_in[3];

    float* out0 = (float*)d_out;              // 4,194,304 floats
    float* p    = out0 + 4194304;             // 67,108,864 floats

    unsigned char* e8  = (unsigned char*)d_ws;        // 64MB fp8
    unsigned char* mo8 = e8 + 67108864;               // 8MB fp8
    float* wpart   = (float*)(e8 + 75497472);         // 3 x 2M fp32 partials
    float* partialW= (float*)(e8 + 100663296);        // [128][4][1024] fp32
    float* invsumW = (float*)(e8 + 102760448);        // [4][1024] fp32

    // fallback scratch in out0's q_out-copy regions (overwritten by k5):
    float* partialF = out0 + 524288;
    float* invsumF  = out0 + 1048576 + 524288;

    const size_t need_big = 176160768ull;

    if (ws_size >= need_big) {
        conv8  <<<dim3(1024),       256, 0, stream>>>(m_out, mo8);
        k1_mfma<<<dim3(4096),       256, 0, stream>>>(m_in, q_in, e8, partialW);
        k2b_red<<<dim3(128),        256, 0, stream>>>(partialW, invsumW);
        k3_big <<<dim3(16, 128, 4), 256, 0, stream>>>(p, e8, invsumW);
        k4_sk8 <<<dim3(512),        256, 0, stream>>>(mo8, e8, out0, wpart);
        k56_fin<<<dim3(2048),       256, 0, stream>>>(out0, wpart, invsumW, q_out);
    } else {
        k1_p    <<<dim3(8, 128, 4), 256, 0, stream>>>(m_in, q_in, p, partialF);
        k2b_red <<<dim3(128),       256, 0, stream>>>(partialF, invsumF);
        k3_small<<<dim3(2048),      256, 0, stream>>>(p, invsumF);
        k4_reg  <<<dim3(16, 8, 4),  256, 0, stream>>>(m_out, p, out0);
        k5_copy <<<dim3(2048),      256, 0, stream>>>(q_out, out0);
    }
}